// Round 11
// baseline (128.672 us; speedup 1.0000x reference)
//
#include <hip/hip_runtime.h>

#define NPTS 32768
#define DIM 256
#define KCODES 1024
#define NSPLIT 8                 // code-splits in the MFMA screen (128 codes/split)
#define BN 256                   // points per screen block
#define BKC 128                  // codes per screen block
#define BK 64                    // K-step (bf16) per staging iter
#define MARGIN 0.08f             // bf16 band: flag + candidate threshold
#define CVT_BLOCKS 2048          // convert grid (plus 4 enorm blocks)

typedef __attribute__((ext_vector_type(8))) short short8v;
typedef __attribute__((ext_vector_type(8))) unsigned short ushort8v;
typedef __attribute__((ext_vector_type(4))) float f32x4;

static __device__ __forceinline__ unsigned short f2bf(float f) {
    unsigned int u = __float_as_uint(f);
    unsigned int r = (u + 0x7fffu + ((u >> 16) & 1u)) >> 16;   // RNE
    return (unsigned short)r;
}

static __device__ __forceinline__ void gload16(const void* g, void* l) {
    __builtin_amdgcn_global_load_lds((const __attribute__((address_space(1))) void*)g,
                                     (__attribute__((address_space(3))) void*)l, 16, 0, 0);
}

// ------- phase 0: f32->bf16 convert (+ per-block sum x^2) and np ||e||^2 -------
__global__ void convert_kernel(const float* __restrict__ X, const float* __restrict__ E,
                               unsigned short* __restrict__ Xb, unsigned short* __restrict__ Eb,
                               float* __restrict__ Cnp, float* __restrict__ xsq_part) {
#pragma clang fp contract(off)
    const int tid = threadIdx.x;
    if (blockIdx.x >= CVT_BLOCKS) {
        // numpy-faithful ||e||^2 (pairwise: 8 accumulators per 128-half)
        int k = (blockIdx.x - CVT_BLOCKS) * 256 + tid;
        const float* e = E + (size_t)k * DIM;
        float half[2];
        for (int h = 0; h < 2; ++h) {
            const float* b = e + h * 128;
            float s[8];
#pragma unroll
            for (int j = 0; j < 8; ++j) { float v = b[j]; s[j] = v * v; }
            for (int i = 8; i < 128; i += 8) {
#pragma unroll
                for (int j = 0; j < 8; ++j) { float v = b[i + j]; s[j] += v * v; }
            }
            half[h] = ((s[0] + s[1]) + (s[2] + s[3])) + ((s[4] + s[5]) + (s[6] + s[7]));
        }
        Cnp[k] = half[0] + half[1];
        return;
    }
    const int total = (NPTS + KCODES) * DIM / 8;
    float xsq = 0.f;
    for (int i = blockIdx.x * 256 + tid; i < total; i += CVT_BLOCKS * 256) {
        size_t e8 = (size_t)i * 8;
        const float* src; unsigned short* dst; size_t off;
        bool isX = e8 < (size_t)NPTS * DIM;
        if (isX) { src = X; dst = Xb; off = e8; }
        else { src = E; dst = Eb; off = e8 - (size_t)NPTS * DIM; }
        float4 f0 = *(const float4*)(src + off);
        float4 f1 = *(const float4*)(src + off + 4);
        ushort8v v;
        v[0] = f2bf(f0.x); v[1] = f2bf(f0.y); v[2] = f2bf(f0.z); v[3] = f2bf(f0.w);
        v[4] = f2bf(f1.x); v[5] = f2bf(f1.y); v[6] = f2bf(f1.z); v[7] = f2bf(f1.w);
        *(ushort8v*)(dst + off) = v;
        if (isX)
            xsq += f0.x * f0.x + f0.y * f0.y + f0.z * f0.z + f0.w * f0.w
                 + f1.x * f1.x + f1.y * f1.y + f1.z * f1.z + f1.w * f1.w;
    }
    __shared__ float red[256];
    red[tid] = xsq;
    __syncthreads();
#pragma unroll
    for (int s = 128; s > 0; s >>= 1) {
        if (tid < s) red[tid] += red[tid + s];
        __syncthreads();
    }
    if (tid == 0) xsq_part[blockIdx.x] = red[0];
}

// ------- phase 1: bf16-MFMA screen — min-value + candidate bitmaps -------
// 1D grid of 1024: bid = split*128 + ptile, so XCD = bid%8 = ptile%8 -> all 8
// splits of one X tile share an XCD L2 (X fetched once). Workspace layouts
// cand[split][p], ws_m1[split][p]: block-private contiguous writes, no
// cross-XCD false sharing. Wave w owns points [w*64, w*64+64) x 128 codes.
__global__ __launch_bounds__(256, 3) void dist_kernel(
        const unsigned short* __restrict__ Xb, const unsigned short* __restrict__ Eb,
        const float* __restrict__ Cnp,
        float* __restrict__ ws_m1, unsigned int* __restrict__ cand,
        int* __restrict__ counters) {
    __shared__ unsigned short xs[BN * BK];    // 32 KB
    __shared__ unsigned short es[BKC * BK];   // 16 KB

    const int tid = threadIdx.x;
    const int lane = tid & 63;
    const int wave = tid >> 6;
    const int lg = lane >> 4, lc = lane & 15;
    const int bid = blockIdx.x;
    const int split = bid >> 7;               // 0..7
    const int pbase = (bid & 127) * BN;
    const int cbase = split * BKC;

    if (bid == 0 && tid == 0) { counters[0] = 0; counters[32] = 0; }

    f32x4 acc[4][8];
#pragma unroll
    for (int i = 0; i < 4; ++i)
#pragma unroll
        for (int j = 0; j < 8; ++j) acc[i][j] = (f32x4){0.f, 0.f, 0.f, 0.f};

    for (int ks = 0; ks < DIM / BK; ++ks) {
        const int k0 = ks * BK;
        __syncthreads();
#pragma unroll
        for (int q = 0; q < 8; ++q) {
            const int B = wave * 8192 + q * 1024 + lane * 16;
            const int row = B >> 7;
            const int cs = ((B >> 4) & 7) ^ (row & 7);
            gload16(Xb + (size_t)(pbase + row) * DIM + k0 + cs * 8,
                    (char*)xs + wave * 8192 + q * 1024);
        }
#pragma unroll
        for (int q = 0; q < 4; ++q) {
            const int B = wave * 4096 + q * 1024 + lane * 16;
            const int row = B >> 7;
            const int cs = ((B >> 4) & 7) ^ (row & 7);
            gload16(Eb + (size_t)(cbase + row) * DIM + k0 + cs * 8,
                    (char*)es + wave * 4096 + q * 1024);
        }
        __syncthreads();
#pragma unroll
        for (int kk = 0; kk < 2; ++kk) {
            short8v a[4];
#pragma unroll
            for (int f = 0; f < 4; ++f) {
                int row = wave * 64 + f * 16 + lc;
                int cs = (kk * 4 + lg) ^ (row & 7);
                a[f] = *(const short8v*)&xs[row * BK + cs * 8];
            }
#pragma unroll
            for (int j = 0; j < 8; ++j) {
                int row = j * 16 + lc;
                int cs = (kk * 4 + lg) ^ (row & 7);
                short8v b = *(const short8v*)&es[row * BK + cs * 8];
#pragma unroll
                for (int i = 0; i < 4; ++i)
                    acc[i][j] = __builtin_amdgcn_mfma_f32_16x16x32_bf16(a[i], b, acc[i][j], 0, 0, 0);
            }
        }
    }

    float en8[8];
#pragma unroll
    for (int j = 0; j < 8; ++j) en8[j] = Cnp[cbase + j * 16 + lc];

    // min-only per point (C/D: col=lane&15 code, row=(lane>>4)*4+reg point)
    float m1[4][4];
#pragma unroll
    for (int i = 0; i < 4; ++i)
#pragma unroll
        for (int r = 0; r < 4; ++r) m1[i][r] = 3.4e38f;
#pragma unroll
    for (int j = 0; j < 8; ++j)
#pragma unroll
        for (int i = 0; i < 4; ++i)
#pragma unroll
            for (int r = 0; r < 4; ++r)
                m1[i][r] = fminf(m1[i][r], __builtin_fmaf(-2.f, acc[i][j][r], en8[j]));
#pragma unroll
    for (int m = 1; m < 16; m <<= 1)
#pragma unroll
        for (int i = 0; i < 4; ++i)
#pragma unroll
            for (int r = 0; r < 4; ++r)
                m1[i][r] = fminf(m1[i][r], __shfl_xor(m1[i][r], m));

    // candidate bitmaps: bit set iff d <= fl(m1 + MARGIN); pack 128 bits -> uint4
#pragma unroll
    for (int i = 0; i < 4; ++i)
#pragma unroll
        for (int r = 0; r < 4; ++r) {
            float thr = m1[i][r] + MARGIN;
            unsigned int sl[8];
#pragma unroll
            for (int j = 0; j < 8; ++j) {
                float d = __builtin_fmaf(-2.f, acc[i][j][r], en8[j]);
                unsigned long long mm = __ballot(d <= thr);
                sl[j] = (unsigned int)((mm >> (lg * 16)) & 0xFFFFull);
            }
            if (lc == 0) {
                int p = pbase + wave * 64 + i * 16 + lg * 4 + r;
                uint4 w4 = { sl[0] | (sl[1] << 16), sl[2] | (sl[3] << 16),
                             sl[4] | (sl[5] << 16), sl[6] | (sl[7] << 16) };
                *(uint4*)&cand[((size_t)split * NPTS + p) * 4] = w4;
                ws_m1[(size_t)split * NPTS + p] = m1[i][r];
            }
        }
}

// ------- phase 2: combine splits, derive index, flag, loss finisher -------
__global__ void resolve_kernel(const float* __restrict__ ws_m1, const unsigned int* __restrict__ cand,
                               int* __restrict__ final_idx, int* __restrict__ list,
                               int* __restrict__ counters,
                               const float* __restrict__ xsq_part, float* __restrict__ v1_part,
                               float* __restrict__ out_loss) {
    const int tid = threadIdx.x;
    const int p = blockIdx.x * 256 + tid;
    float m[8];
#pragma unroll
    for (int s = 0; s < NSPLIT; ++s) m[s] = ws_m1[(size_t)s * NPTS + p];
    float v1 = m[0]; int sstar = 0;
#pragma unroll
    for (int s = 1; s < NSPLIT; ++s)
        if (m[s] < v1) { v1 = m[s]; sstar = s; }
    float thr = v1 + MARGIN;                // same rounded op as dist's ballot threshold
    bool flag = false;
#pragma unroll
    for (int s = 0; s < NSPLIT; ++s)
        if (s != sstar && m[s] <= thr) flag = true;
    uint4 w4 = *(const uint4*)&cand[((size_t)sstar * NPTS + p) * 4];
    int pc = __builtin_popcount(w4.x) + __builtin_popcount(w4.y)
           + __builtin_popcount(w4.z) + __builtin_popcount(w4.w);
    flag = flag || (pc > 1);
    int idx;
    if (w4.x)      idx = __builtin_ctz(w4.x);
    else if (w4.y) idx = 32 + __builtin_ctz(w4.y);
    else if (w4.z) idx = 64 + __builtin_ctz(w4.z);
    else           idx = 96 + __builtin_ctz(w4.w);
    final_idx[p] = sstar * BKC + idx;
    if (flag) {
        int slot = atomicAdd(&counters[0], 1);
        list[slot] = p;
    }

    // block partial of sum v1 (loss = 1.25*(sum v1 + sum x^2)/(N*D), error ~1e-5)
    __shared__ float red[256];
    red[tid] = v1;
    __syncthreads();
#pragma unroll
    for (int s = 128; s > 0; s >>= 1) {
        if (tid < s) red[tid] += red[tid + s];
        __syncthreads();
    }
    if (tid == 0) v1_part[blockIdx.x] = red[0];

    __shared__ int amlast;
    if (tid == 0) {
        __threadfence();
        amlast = (atomicAdd(&counters[32], 1) == (int)gridDim.x - 1);
    }
    __syncthreads();
    if (amlast) {
        __threadfence();
        double s = 0.0;
        for (int i = tid; i < CVT_BLOCKS; i += 256) s += (double)xsq_part[i];
        for (int i = tid; i < NPTS / 256; i += 256) s += (double)v1_part[i];
        __shared__ double dred[256];
        dred[tid] = s;
        __syncthreads();
#pragma unroll
        for (int t = 128; t > 0; t >>= 1) {
            if (tid < t) dred[tid] += dred[tid + t];
            __syncthreads();
        }
        if (tid == 0)
            out_loss[0] = (float)(1.25 * dred[0] / (double)((size_t)NPTS * DIM));
    }
}

// ------- phase 3: np-emulating rescore over candidate bitmaps -------
// One flagged point per wave; lane<32 owns one bitmap word; per set bit:
// d = fl32(fl32(A - 2*B) + C), B = sequential ascending-d fp32 fma chain,
// A = np-pairwise sum x^2, C = Cnp — bit-identical to rounds 3-10.
__global__ __launch_bounds__(256) void rescore_np_kernel(
        const float* __restrict__ X, const float* __restrict__ E,
        const float* __restrict__ Cnp, const unsigned int* __restrict__ cand,
        const int* __restrict__ list, const int* __restrict__ counters,
        int* __restrict__ final_idx) {
#pragma clang fp contract(off)
    const int tid = threadIdx.x;
    const int lane = tid & 63;
    const int wave = tid >> 6;
    const int cnt = counters[0];
    __shared__ float xsh[4][DIM];

    for (int base = blockIdx.x * 4; base < cnt; base += gridDim.x * 4) {
        const int li = base + wave;
        const bool active = (li < cnt);
        const int p = list[active ? li : (cnt - 1)];
        __syncthreads();
        *(float4*)&xsh[wave][lane * 4] = *(const float4*)(X + (size_t)p * DIM + lane * 4);
        __syncthreads();

        float s = 0.f;
        if (lane < 16) {
            const int h = lane >> 3, j = lane & 7;
            float v = xsh[wave][h * 128 + j];
            s = v * v;
            for (int i = 8; i < 128; i += 8) {
                float w = xsh[wave][h * 128 + i + j];
                s += w * w;
            }
        }
        float t0 = __shfl(s, 0), t1 = __shfl(s, 1), t2 = __shfl(s, 2), t3 = __shfl(s, 3);
        float t4 = __shfl(s, 4), t5 = __shfl(s, 5), t6 = __shfl(s, 6), t7 = __shfl(s, 7);
        float u0 = __shfl(s, 8), u1 = __shfl(s, 9), u2 = __shfl(s, 10), u3 = __shfl(s, 11);
        float u4 = __shfl(s, 12), u5 = __shfl(s, 13), u6 = __shfl(s, 14), u7 = __shfl(s, 15);
        const float A = (((t0 + t1) + (t2 + t3)) + ((t4 + t5) + (t6 + t7)))
                      + (((u0 + u1) + (u2 + u3)) + ((u4 + u5) + (u6 + u7)));

        float bv = 3.4e38f; int bi = 0x7FFFFFFF;
        if (lane < 32) {
            // transposed layout: word (lane&3) of split (lane>>2)
            unsigned int bits = cand[(((size_t)(lane >> 2)) * NPTS + p) * 4 + (lane & 3)];
            const int cb = (lane >> 2) * 128 + (lane & 3) * 32;
            while (bits) {
                int t = __builtin_ctz(bits);
                bits &= bits - 1;
                int c = cb + t;
                const float4* er4 = (const float4*)(E + (size_t)c * DIM);
                float acc = 0.f;
                for (int d4 = 0; d4 < DIM / 4; ++d4) {
                    float4 e4 = er4[d4];
                    float4 x4 = *(const float4*)&xsh[wave][d4 * 4];
                    acc = __builtin_fmaf(x4.x, e4.x, acc);
                    acc = __builtin_fmaf(x4.y, e4.y, acc);
                    acc = __builtin_fmaf(x4.z, e4.z, acc);
                    acc = __builtin_fmaf(x4.w, e4.w, acc);
                }
                float tt = A - 2.0f * acc;
                float dnp = tt + Cnp[c];
                if (dnp < bv) { bv = dnp; bi = c; }
            }
        }
#pragma unroll
        for (int m = 1; m < 64; m <<= 1) {
            float ov = __shfl_xor(bv, m);
            int oi = __shfl_xor(bi, m);
            if (ov < bv || (ov == bv && oi < bi)) { bv = ov; bi = oi; }
        }
        if (active && lane == 0) final_idx[p] = bi;
    }
}

// ------- phase 4: gather — write quantized rows + indices (no X read) -------
__global__ void gather_kernel(const float* __restrict__ E, const int* __restrict__ final_idx,
                              float* __restrict__ out_q, float* __restrict__ out_idx) {
    const int tid = threadIdx.x;
    const int p = blockIdx.x * 16 + (tid >> 4);
    const int c = tid & 15;
    const int bi = final_idx[p];
#pragma unroll
    for (int k = 0; k < 4; ++k) {
        int d4 = c + k * 16;
        float4 e4 = *(const float4*)(E + (size_t)bi * DIM + d4 * 4);
        *(float4*)(out_q + (size_t)p * DIM + d4 * 4) = e4;
    }
    if (c == 0) out_idx[p] = (float)bi;
}

extern "C" void kernel_launch(void* const* d_in, const int* in_sizes, int n_in,
                              void* d_out, int out_size, void* d_ws, size_t ws_size,
                              hipStream_t stream) {
    const float* X = (const float*)d_in[0];   // [32768, 256]
    const float* E = (const float*)d_in[1];   // [1024, 256]
    float* out = (float*)d_out;
    float* out_q = out;                                 // 8388608 floats
    float* out_loss = out + (size_t)NPTS * DIM;         // 1 float
    float* out_idx = out + (size_t)NPTS * DIM + 1;      // 32768 floats

    // staging inside out_q (fully rewritten by gather afterward):
    // Xb (16.8MB) + Eb (0.5MB) + cand (4.2MB) = 21.5MB < 33.5MB
    unsigned short* Xb = (unsigned short*)d_out;
    unsigned short* Eb = Xb + (size_t)NPTS * DIM;
    unsigned int* cand = (unsigned int*)(Eb + (size_t)KCODES * DIM);  // [8][NPTS][4] u32

    float* ws = (float*)d_ws;
    float* Cnp = ws;                                    // 1024
    float* ws_m1 = Cnp + KCODES;                        // [8][NPTS] floats (1MB)
    int* final_idx = (int*)(ws_m1 + (size_t)NPTS * NSPLIT);  // 32768 ints
    int* counters = final_idx + NPTS;                   // 64 ints ([0]=flag cnt, [32]=done)
    int* list = counters + 64;                          // 32768 ints
    float* xsq_part = (float*)(list + NPTS);            // 2048 floats
    float* v1_part = xsq_part + CVT_BLOCKS;             // 128 floats

    convert_kernel<<<CVT_BLOCKS + KCODES / 256, 256, 0, stream>>>(X, E, Xb, Eb, Cnp, xsq_part);
    dist_kernel<<<NSPLIT * (NPTS / BN), 256, 0, stream>>>(Xb, Eb, Cnp, ws_m1, cand, counters);
    resolve_kernel<<<NPTS / 256, 256, 0, stream>>>(ws_m1, cand, final_idx, list, counters,
                                                   xsq_part, v1_part, out_loss);
    rescore_np_kernel<<<512, 256, 0, stream>>>(X, E, Cnp, cand, list, counters, final_idx);
    gather_kernel<<<NPTS / 16, 256, 0, stream>>>(E, final_idx, out_q, out_idx);
}

// Round 12
// 92.796 us; speedup vs baseline: 1.3866x; 1.3866x over previous
//
#include <hip/hip_runtime.h>

#define NPTS 32768
#define DIM 256
#define KCODES 1024
#define NSPLIT 8                 // code-splits in the MFMA screen (128 codes/block)
#define BN 256                   // points per screen block
#define BKC 128                  // codes per screen block
#define BK 64                    // K-step (bf16) per staging iter
#define MARGIN 0.08f             // bf16 band: flag + candidate threshold

typedef __attribute__((ext_vector_type(8))) short short8v;
typedef __attribute__((ext_vector_type(8))) unsigned short ushort8v;
typedef __attribute__((ext_vector_type(4))) float f32x4;

static __device__ __forceinline__ unsigned short f2bf(float f) {
    unsigned int u = __float_as_uint(f);
    unsigned int r = (u + 0x7fffu + ((u >> 16) & 1u)) >> 16;   // RNE
    return (unsigned short)r;
}

static __device__ __forceinline__ void gload16(const void* g, void* l) {
    __builtin_amdgcn_global_load_lds((const __attribute__((address_space(1))) void*)g,
                                     (__attribute__((address_space(3))) void*)l, 16, 0, 0);
}

// ---------------- phase -1: f32 -> bf16 conversion of X and E ----------------
__global__ void convert_kernel(const float* __restrict__ X, const float* __restrict__ E,
                               unsigned short* __restrict__ Xb, unsigned short* __restrict__ Eb) {
    int i = blockIdx.x * 256 + threadIdx.x;
    size_t e8 = (size_t)i * 8;
    const float* src; unsigned short* dst; size_t off;
    if (e8 < (size_t)NPTS * DIM) { src = X; dst = Xb; off = e8; }
    else { src = E; dst = Eb; off = e8 - (size_t)NPTS * DIM; }
    float4 f0 = *(const float4*)(src + off);
    float4 f1 = *(const float4*)(src + off + 4);
    ushort8v v;
    v[0] = f2bf(f0.x); v[1] = f2bf(f0.y); v[2] = f2bf(f0.z); v[3] = f2bf(f0.w);
    v[4] = f2bf(f1.x); v[5] = f2bf(f1.y); v[6] = f2bf(f1.z); v[7] = f2bf(f1.w);
    *(ushort8v*)(dst + off) = v;
}

// ---------------- phase 0: numpy-faithful ||e||^2 (pairwise emulation) + counter zero ----------------
__global__ void enormnp_kernel(const float* __restrict__ E, float* __restrict__ Cnp,
                               int* __restrict__ counter) {
#pragma clang fp contract(off)
    if (blockIdx.x == 0 && threadIdx.x == 0) counter[0] = 0;
    int k = blockIdx.x * 256 + threadIdx.x;
    const float* e = E + (size_t)k * DIM;
    float half[2];
    for (int h = 0; h < 2; ++h) {
        const float* b = e + h * 128;
        float s[8];
#pragma unroll
        for (int j = 0; j < 8; ++j) { float v = b[j]; s[j] = v * v; }
        for (int i = 8; i < 128; i += 8) {
#pragma unroll
            for (int j = 0; j < 8; ++j) { float v = b[i + j]; s[j] += v * v; }
        }
        half[h] = ((s[0] + s[1]) + (s[2] + s[3])) + ((s[4] + s[5]) + (s[6] + s[7]));
    }
    Cnp[k] = half[0] + half[1];
}

// ---------------- phase 1: bf16-MFMA screen — min-value + candidate bitmaps ----------------
// grid (NPTS/256, 8), 256 threads = 4 waves; wave w owns points [w*64, w*64+64)
// x all 128 codes. Linear LDS, gload_lds w=16 with XOR-swizzled global source;
// same swizzle on ds_read (rule #21). Value-only min; index derived in resolve.
__global__ __launch_bounds__(256, 2) void dist_kernel(
        const unsigned short* __restrict__ Xb, const unsigned short* __restrict__ Eb,
        const float* __restrict__ Cnp,
        float* __restrict__ ws_m1, unsigned int* __restrict__ cand) {
    __shared__ unsigned short xs[BN * BK];    // 32 KB
    __shared__ unsigned short es[BKC * BK];   // 16 KB

    const int tid = threadIdx.x;
    const int lane = tid & 63;
    const int wave = tid >> 6;
    const int lg = lane >> 4, lc = lane & 15;
    const int pbase = blockIdx.x * BN;
    const int split = blockIdx.y;
    const int cbase = split * BKC;

    f32x4 acc[4][8];
#pragma unroll
    for (int i = 0; i < 4; ++i)
#pragma unroll
        for (int j = 0; j < 8; ++j) acc[i][j] = (f32x4){0.f, 0.f, 0.f, 0.f};

    for (int ks = 0; ks < DIM / BK; ++ks) {
        const int k0 = ks * BK;
        __syncthreads();
#pragma unroll
        for (int q = 0; q < 8; ++q) {
            const int B = wave * 8192 + q * 1024 + lane * 16;
            const int row = B >> 7;
            const int cs = ((B >> 4) & 7) ^ (row & 7);
            gload16(Xb + (size_t)(pbase + row) * DIM + k0 + cs * 8,
                    (char*)xs + wave * 8192 + q * 1024);
        }
#pragma unroll
        for (int q = 0; q < 4; ++q) {
            const int B = wave * 4096 + q * 1024 + lane * 16;
            const int row = B >> 7;
            const int cs = ((B >> 4) & 7) ^ (row & 7);
            gload16(Eb + (size_t)(cbase + row) * DIM + k0 + cs * 8,
                    (char*)es + wave * 4096 + q * 1024);
        }
        __syncthreads();
#pragma unroll
        for (int kk = 0; kk < 2; ++kk) {
            short8v a[4];
#pragma unroll
            for (int f = 0; f < 4; ++f) {
                int row = wave * 64 + f * 16 + lc;
                int cs = (kk * 4 + lg) ^ (row & 7);
                a[f] = *(const short8v*)&xs[row * BK + cs * 8];
            }
#pragma unroll
            for (int j = 0; j < 8; ++j) {
                int row = j * 16 + lc;
                int cs = (kk * 4 + lg) ^ (row & 7);
                short8v b = *(const short8v*)&es[row * BK + cs * 8];
#pragma unroll
                for (int i = 0; i < 4; ++i)
                    acc[i][j] = __builtin_amdgcn_mfma_f32_16x16x32_bf16(a[i], b, acc[i][j], 0, 0, 0);
            }
        }
    }

    float en8[8];
#pragma unroll
    for (int j = 0; j < 8; ++j) en8[j] = Cnp[cbase + j * 16 + lc];

    // min-only per point (C/D: col=lane&15 code, row=(lane>>4)*4+reg point)
    float m1[4][4];
#pragma unroll
    for (int i = 0; i < 4; ++i)
#pragma unroll
        for (int r = 0; r < 4; ++r) m1[i][r] = 3.4e38f;
#pragma unroll
    for (int j = 0; j < 8; ++j)
#pragma unroll
        for (int i = 0; i < 4; ++i)
#pragma unroll
            for (int r = 0; r < 4; ++r)
                m1[i][r] = fminf(m1[i][r], __builtin_fmaf(-2.f, acc[i][j][r], en8[j]));
#pragma unroll
    for (int m = 1; m < 16; m <<= 1)
#pragma unroll
        for (int i = 0; i < 4; ++i)
#pragma unroll
            for (int r = 0; r < 4; ++r)
                m1[i][r] = fminf(m1[i][r], __shfl_xor(m1[i][r], m));

    // candidate bitmaps: bit set iff d <= fl(m1 + MARGIN); pack 128 bits -> uint4
#pragma unroll
    for (int i = 0; i < 4; ++i)
#pragma unroll
        for (int r = 0; r < 4; ++r) {
            float thr = m1[i][r] + MARGIN;
            unsigned int sl[8];
#pragma unroll
            for (int j = 0; j < 8; ++j) {
                float d = __builtin_fmaf(-2.f, acc[i][j][r], en8[j]);
                unsigned long long mm = __ballot(d <= thr);
                sl[j] = (unsigned int)((mm >> (lg * 16)) & 0xFFFFull);
            }
            if (lc == 0) {
                int p = pbase + wave * 64 + i * 16 + lg * 4 + r;
                uint4 w4 = { sl[0] | (sl[1] << 16), sl[2] | (sl[3] << 16),
                             sl[4] | (sl[5] << 16), sl[6] | (sl[7] << 16) };
                *(uint4*)&cand[((size_t)p * NSPLIT + split) * 4] = w4;
                ws_m1[(size_t)p * NSPLIT + split] = m1[i][r];
            }
        }
}

// ---------------- phase 2: combine splits, derive index, flag ambiguous ----------------
__global__ void resolve_kernel(const float* __restrict__ ws_m1, const unsigned int* __restrict__ cand,
                               int* __restrict__ final_idx, int* __restrict__ list,
                               int* __restrict__ counter) {
    const int tid = threadIdx.x;
    const int p = blockIdx.x * 256 + tid;
    float4 ma = *(const float4*)&ws_m1[(size_t)p * NSPLIT];
    float4 mb = *(const float4*)&ws_m1[(size_t)p * NSPLIT + 4];
    float m[8] = { ma.x, ma.y, ma.z, ma.w, mb.x, mb.y, mb.z, mb.w };
    float v1 = m[0]; int sstar = 0;
#pragma unroll
    for (int s = 1; s < NSPLIT; ++s)
        if (m[s] < v1) { v1 = m[s]; sstar = s; }
    float thr = v1 + MARGIN;                // same rounded op as dist's ballot threshold
    bool flag = false;
#pragma unroll
    for (int s = 0; s < NSPLIT; ++s)
        if (s != sstar && m[s] <= thr) flag = true;
    uint4 w4 = *(const uint4*)&cand[((size_t)p * NSPLIT + sstar) * 4];
    int pc = __builtin_popcount(w4.x) + __builtin_popcount(w4.y)
           + __builtin_popcount(w4.z) + __builtin_popcount(w4.w);
    flag = flag || (pc > 1);
    int idx;
    if (w4.x)      idx = __builtin_ctz(w4.x);
    else if (w4.y) idx = 32 + __builtin_ctz(w4.y);
    else if (w4.z) idx = 64 + __builtin_ctz(w4.z);
    else           idx = 96 + __builtin_ctz(w4.w);
    final_idx[p] = sstar * BKC + idx;
    if (flag) {
        int slot = atomicAdd(counter, 1);
        list[slot] = p;
    }
}

// ---------------- phase 3: np-emulating rescore over candidate bitmaps ----------------
// One flagged point per wave; lane<32 owns one bitmap word; per set bit:
// d = fl32(fl32(A - 2*B) + C), B = sequential ascending-d fp32 fma chain,
// A = np-pairwise sum x^2, C = Cnp — bit-identical to rounds 3-11.
__global__ __launch_bounds__(256) void rescore_np_kernel(
        const float* __restrict__ X, const float* __restrict__ E,
        const float* __restrict__ Cnp, const unsigned int* __restrict__ cand,
        const int* __restrict__ list, const int* __restrict__ counter,
        int* __restrict__ final_idx) {
#pragma clang fp contract(off)
    const int tid = threadIdx.x;
    const int lane = tid & 63;
    const int wave = tid >> 6;
    const int cnt = counter[0];
    __shared__ float xsh[4][DIM];

    for (int base = blockIdx.x * 4; base < cnt; base += gridDim.x * 4) {
        const int li = base + wave;
        const bool active = (li < cnt);
        const int p = list[active ? li : (cnt - 1)];
        __syncthreads();
        *(float4*)&xsh[wave][lane * 4] = *(const float4*)(X + (size_t)p * DIM + lane * 4);
        __syncthreads();

        float s = 0.f;
        if (lane < 16) {
            const int h = lane >> 3, j = lane & 7;
            float v = xsh[wave][h * 128 + j];
            s = v * v;
            for (int i = 8; i < 128; i += 8) {
                float w = xsh[wave][h * 128 + i + j];
                s += w * w;
            }
        }
        float t0 = __shfl(s, 0), t1 = __shfl(s, 1), t2 = __shfl(s, 2), t3 = __shfl(s, 3);
        float t4 = __shfl(s, 4), t5 = __shfl(s, 5), t6 = __shfl(s, 6), t7 = __shfl(s, 7);
        float u0 = __shfl(s, 8), u1 = __shfl(s, 9), u2 = __shfl(s, 10), u3 = __shfl(s, 11);
        float u4 = __shfl(s, 12), u5 = __shfl(s, 13), u6 = __shfl(s, 14), u7 = __shfl(s, 15);
        const float A = (((t0 + t1) + (t2 + t3)) + ((t4 + t5) + (t6 + t7)))
                      + (((u0 + u1) + (u2 + u3)) + ((u4 + u5) + (u6 + u7)));

        float bv = 3.4e38f; int bi = 0x7FFFFFFF;
        if (lane < 32) {
            unsigned int bits = cand[(size_t)p * 32 + lane];
            const int cb = (lane >> 2) * 128 + (lane & 3) * 32;
            while (bits) {
                int t = __builtin_ctz(bits);
                bits &= bits - 1;
                int c = cb + t;
                const float4* er4 = (const float4*)(E + (size_t)c * DIM);
                float acc = 0.f;
                for (int d4 = 0; d4 < DIM / 4; ++d4) {
                    float4 e4 = er4[d4];
                    float4 x4 = *(const float4*)&xsh[wave][d4 * 4];
                    acc = __builtin_fmaf(x4.x, e4.x, acc);
                    acc = __builtin_fmaf(x4.y, e4.y, acc);
                    acc = __builtin_fmaf(x4.z, e4.z, acc);
                    acc = __builtin_fmaf(x4.w, e4.w, acc);
                }
                float tt = A - 2.0f * acc;
                float dnp = tt + Cnp[c];
                if (dnp < bv) { bv = dnp; bi = c; }
            }
        }
#pragma unroll
        for (int m = 1; m < 64; m <<= 1) {
            float ov = __shfl_xor(bv, m);
            int oi = __shfl_xor(bi, m);
            if (ov < bv || (ov == bv && oi < bi)) { bv = ov; bi = oi; }
        }
        if (active && lane == 0) final_idx[p] = bi;
    }
}

// ---------------- phase 4: gather, write quantized/indices, loss partials ----------------
__global__ void gather_kernel(const float* __restrict__ X, const float* __restrict__ E,
                              const int* __restrict__ final_idx,
                              float* __restrict__ out_q, float* __restrict__ out_idx,
                              float* __restrict__ ws_part) {
    const int tid = threadIdx.x;
    const int p = blockIdx.x * 16 + (tid >> 4);
    const int c = tid & 15;
    const int bi = final_idx[p];

    float ls = 0.f;
#pragma unroll
    for (int k = 0; k < 4; ++k) {
        int d4 = c + k * 16;
        float4 e4 = *(const float4*)(E + (size_t)bi * DIM + d4 * 4);
        float4 x4 = *(const float4*)(X + (size_t)p * DIM + d4 * 4);
        *(float4*)(out_q + (size_t)p * DIM + d4 * 4) = e4;
        float dx = e4.x - x4.x, dy = e4.y - x4.y, dz = e4.z - x4.z, dw = e4.w - x4.w;
        ls += dx * dx + dy * dy + dz * dz + dw * dw;
    }
    if (c == 0) out_idx[p] = (float)bi;

    __shared__ float red[256];
    red[tid] = ls;
    __syncthreads();
#pragma unroll
    for (int s = 128; s > 0; s >>= 1) {
        if (tid < s) red[tid] += red[tid + s];
        __syncthreads();
    }
    if (tid == 0) ws_part[blockIdx.x] = red[0];
}

// ---------------- phase 5: final loss reduce ----------------
__global__ void loss_kernel(const float* __restrict__ ws_part, float* __restrict__ out_loss) {
    const int tid = threadIdx.x;
    float s = 0.f;
    for (int i = tid; i < NPTS / 16; i += 256) s += ws_part[i];
    __shared__ float red[256];
    red[tid] = s;
    __syncthreads();
#pragma unroll
    for (int t = 128; t > 0; t >>= 1) {
        if (tid < t) red[tid] += red[tid + t];
        __syncthreads();
    }
    if (tid == 0)
        out_loss[0] = (1.f + 0.25f) * red[0] / (float)((size_t)NPTS * DIM);
}

extern "C" void kernel_launch(void* const* d_in, const int* in_sizes, int n_in,
                              void* d_out, int out_size, void* d_ws, size_t ws_size,
                              hipStream_t stream) {
    const float* X = (const float*)d_in[0];   // [32768, 256]
    const float* E = (const float*)d_in[1];   // [1024, 256]
    float* out = (float*)d_out;
    float* out_q = out;                                 // 8388608 floats
    float* out_loss = out + (size_t)NPTS * DIM;         // 1 float
    float* out_idx = out + (size_t)NPTS * DIM + 1;      // 32768 floats

    // staging inside out_q (fully rewritten by gather afterward):
    // Xb (16.8MB) + Eb (0.5MB) + cand (4.2MB) = 21.5MB < 33.5MB
    unsigned short* Xb = (unsigned short*)d_out;
    unsigned short* Eb = Xb + (size_t)NPTS * DIM;
    unsigned int* cand = (unsigned int*)(Eb + (size_t)KCODES * DIM);  // [NPTS][8][4] u32

    float* ws = (float*)d_ws;
    float* Cnp = ws;                                    // 1024
    float* ws_m1 = Cnp + KCODES;                        // [NPTS][8] floats (1MB)
    int* final_idx = (int*)(ws_m1 + (size_t)NPTS * NSPLIT);  // 32768 ints
    int* counter = final_idx + NPTS;                    // 1 int (+63 pad)
    int* list = counter + 64;                           // 32768 ints
    float* ws_part = (float*)(list + NPTS);             // 2048 floats

    convert_kernel<<<(NPTS + KCODES) * DIM / 8 / 256, 256, 0, stream>>>(X, E, Xb, Eb);
    enormnp_kernel<<<KCODES / 256, 256, 0, stream>>>(E, Cnp, counter);
    dist_kernel<<<dim3(NPTS / BN, NSPLIT), 256, 0, stream>>>(Xb, Eb, Cnp, ws_m1, cand);
    resolve_kernel<<<NPTS / 256, 256, 0, stream>>>(ws_m1, cand, final_idx, list, counter);
    rescore_np_kernel<<<512, 256, 0, stream>>>(X, E, Cnp, cand, list, counter, final_idx);
    gather_kernel<<<NPTS / 16, 256, 0, stream>>>(X, E, final_idx, out_q, out_idx, ws_part);
    loss_kernel<<<1, 256, 0, stream>>>(ws_part, out_loss);
}

// Round 13
// 89.691 us; speedup vs baseline: 1.4346x; 1.0346x over previous
//
#include <hip/hip_runtime.h>

#define NPTS 32768
#define DIM 256
#define KCODES 1024
#define NSPLIT 8                 // code-splits in the MFMA screen (128 codes/block)
#define BN 256                   // points per screen block
#define BKC 128                  // codes per screen block
#define BK 64                    // K-step (bf16) per staging iter
#define MARGIN 0.08f             // bf16 band: flag + candidate threshold
#define CVT_BLOCKS 2048          // convert grid (plus 4 enorm blocks)

typedef __attribute__((ext_vector_type(8))) short short8v;
typedef __attribute__((ext_vector_type(8))) unsigned short ushort8v;
typedef __attribute__((ext_vector_type(4))) float f32x4;

static __device__ __forceinline__ unsigned short f2bf(float f) {
    unsigned int u = __float_as_uint(f);
    unsigned int r = (u + 0x7fffu + ((u >> 16) & 1u)) >> 16;   // RNE
    return (unsigned short)r;
}

static __device__ __forceinline__ void gload16(const void* g, void* l) {
    __builtin_amdgcn_global_load_lds((const __attribute__((address_space(1))) void*)g,
                                     (__attribute__((address_space(3))) void*)l, 16, 0, 0);
}

// ------- phase 0: f32->bf16 convert (+ per-block sum x^2) and np ||e||^2 -------
__global__ void convert_kernel(const float* __restrict__ X, const float* __restrict__ E,
                               unsigned short* __restrict__ Xb, unsigned short* __restrict__ Eb,
                               float* __restrict__ Cnp, float* __restrict__ xsq_part,
                               int* __restrict__ counters) {
#pragma clang fp contract(off)
    const int tid = threadIdx.x;
    if (blockIdx.x == 0 && tid == 0) { counters[0] = 0; counters[32] = 0; }
    if (blockIdx.x >= CVT_BLOCKS) {
        // numpy-faithful ||e||^2 (pairwise: 8 accumulators per 128-half)
        int k = (blockIdx.x - CVT_BLOCKS) * 256 + tid;
        const float* e = E + (size_t)k * DIM;
        float half[2];
        for (int h = 0; h < 2; ++h) {
            const float* b = e + h * 128;
            float s[8];
#pragma unroll
            for (int j = 0; j < 8; ++j) { float v = b[j]; s[j] = v * v; }
            for (int i = 8; i < 128; i += 8) {
#pragma unroll
                for (int j = 0; j < 8; ++j) { float v = b[i + j]; s[j] += v * v; }
            }
            half[h] = ((s[0] + s[1]) + (s[2] + s[3])) + ((s[4] + s[5]) + (s[6] + s[7]));
        }
        Cnp[k] = half[0] + half[1];
        return;
    }
    const int total = (NPTS + KCODES) * DIM / 8;
    float xsq = 0.f;
    for (int i = blockIdx.x * 256 + tid; i < total; i += CVT_BLOCKS * 256) {
        size_t e8 = (size_t)i * 8;
        const float* src; unsigned short* dst; size_t off;
        bool isX = e8 < (size_t)NPTS * DIM;
        if (isX) { src = X; dst = Xb; off = e8; }
        else { src = E; dst = Eb; off = e8 - (size_t)NPTS * DIM; }
        float4 f0 = *(const float4*)(src + off);
        float4 f1 = *(const float4*)(src + off + 4);
        ushort8v v;
        v[0] = f2bf(f0.x); v[1] = f2bf(f0.y); v[2] = f2bf(f0.z); v[3] = f2bf(f0.w);
        v[4] = f2bf(f1.x); v[5] = f2bf(f1.y); v[6] = f2bf(f1.z); v[7] = f2bf(f1.w);
        *(ushort8v*)(dst + off) = v;
        if (isX)
            xsq += f0.x * f0.x + f0.y * f0.y + f0.z * f0.z + f0.w * f0.w
                 + f1.x * f1.x + f1.y * f1.y + f1.z * f1.z + f1.w * f1.w;
    }
    __shared__ float red[256];
    red[tid] = xsq;
    __syncthreads();
#pragma unroll
    for (int s = 128; s > 0; s >>= 1) {
        if (tid < s) red[tid] += red[tid + s];
        __syncthreads();
    }
    if (tid == 0) xsq_part[blockIdx.x] = red[0];
}

// ------- phase 1: bf16-MFMA screen — min-value + candidate bitmaps (R12 champion, verbatim) -------
// grid (NPTS/256, 8), 256 threads = 4 waves; wave w owns points [w*64, w*64+64)
// x all 128 codes. Linear LDS, gload_lds w=16 with XOR-swizzled global source;
// same swizzle on ds_read (rule #21). Value-only min; index derived in resolve.
__global__ __launch_bounds__(256, 2) void dist_kernel(
        const unsigned short* __restrict__ Xb, const unsigned short* __restrict__ Eb,
        const float* __restrict__ Cnp,
        float* __restrict__ ws_m1, unsigned int* __restrict__ cand) {
    __shared__ unsigned short xs[BN * BK];    // 32 KB
    __shared__ unsigned short es[BKC * BK];   // 16 KB

    const int tid = threadIdx.x;
    const int lane = tid & 63;
    const int wave = tid >> 6;
    const int lg = lane >> 4, lc = lane & 15;
    const int pbase = blockIdx.x * BN;
    const int split = blockIdx.y;
    const int cbase = split * BKC;

    f32x4 acc[4][8];
#pragma unroll
    for (int i = 0; i < 4; ++i)
#pragma unroll
        for (int j = 0; j < 8; ++j) acc[i][j] = (f32x4){0.f, 0.f, 0.f, 0.f};

    for (int ks = 0; ks < DIM / BK; ++ks) {
        const int k0 = ks * BK;
        __syncthreads();
#pragma unroll
        for (int q = 0; q < 8; ++q) {
            const int B = wave * 8192 + q * 1024 + lane * 16;
            const int row = B >> 7;
            const int cs = ((B >> 4) & 7) ^ (row & 7);
            gload16(Xb + (size_t)(pbase + row) * DIM + k0 + cs * 8,
                    (char*)xs + wave * 8192 + q * 1024);
        }
#pragma unroll
        for (int q = 0; q < 4; ++q) {
            const int B = wave * 4096 + q * 1024 + lane * 16;
            const int row = B >> 7;
            const int cs = ((B >> 4) & 7) ^ (row & 7);
            gload16(Eb + (size_t)(cbase + row) * DIM + k0 + cs * 8,
                    (char*)es + wave * 4096 + q * 1024);
        }
        __syncthreads();
#pragma unroll
        for (int kk = 0; kk < 2; ++kk) {
            short8v a[4];
#pragma unroll
            for (int f = 0; f < 4; ++f) {
                int row = wave * 64 + f * 16 + lc;
                int cs = (kk * 4 + lg) ^ (row & 7);
                a[f] = *(const short8v*)&xs[row * BK + cs * 8];
            }
#pragma unroll
            for (int j = 0; j < 8; ++j) {
                int row = j * 16 + lc;
                int cs = (kk * 4 + lg) ^ (row & 7);
                short8v b = *(const short8v*)&es[row * BK + cs * 8];
#pragma unroll
                for (int i = 0; i < 4; ++i)
                    acc[i][j] = __builtin_amdgcn_mfma_f32_16x16x32_bf16(a[i], b, acc[i][j], 0, 0, 0);
            }
        }
    }

    float en8[8];
#pragma unroll
    for (int j = 0; j < 8; ++j) en8[j] = Cnp[cbase + j * 16 + lc];

    // min-only per point (C/D: col=lane&15 code, row=(lane>>4)*4+reg point)
    float m1[4][4];
#pragma unroll
    for (int i = 0; i < 4; ++i)
#pragma unroll
        for (int r = 0; r < 4; ++r) m1[i][r] = 3.4e38f;
#pragma unroll
    for (int j = 0; j < 8; ++j)
#pragma unroll
        for (int i = 0; i < 4; ++i)
#pragma unroll
            for (int r = 0; r < 4; ++r)
                m1[i][r] = fminf(m1[i][r], __builtin_fmaf(-2.f, acc[i][j][r], en8[j]));
#pragma unroll
    for (int m = 1; m < 16; m <<= 1)
#pragma unroll
        for (int i = 0; i < 4; ++i)
#pragma unroll
            for (int r = 0; r < 4; ++r)
                m1[i][r] = fminf(m1[i][r], __shfl_xor(m1[i][r], m));

    // candidate bitmaps: bit set iff d <= fl(m1 + MARGIN); pack 128 bits -> uint4
#pragma unroll
    for (int i = 0; i < 4; ++i)
#pragma unroll
        for (int r = 0; r < 4; ++r) {
            float thr = m1[i][r] + MARGIN;
            unsigned int sl[8];
#pragma unroll
            for (int j = 0; j < 8; ++j) {
                float d = __builtin_fmaf(-2.f, acc[i][j][r], en8[j]);
                unsigned long long mm = __ballot(d <= thr);
                sl[j] = (unsigned int)((mm >> (lg * 16)) & 0xFFFFull);
            }
            if (lc == 0) {
                int p = pbase + wave * 64 + i * 16 + lg * 4 + r;
                uint4 w4 = { sl[0] | (sl[1] << 16), sl[2] | (sl[3] << 16),
                             sl[4] | (sl[5] << 16), sl[6] | (sl[7] << 16) };
                *(uint4*)&cand[((size_t)p * NSPLIT + split) * 4] = w4;
                ws_m1[(size_t)p * NSPLIT + split] = m1[i][r];
            }
        }
}

// ------- phase 2: combine splits, derive index, flag, loss finisher -------
__global__ void resolve_kernel(const float* __restrict__ ws_m1, const unsigned int* __restrict__ cand,
                               int* __restrict__ final_idx, int* __restrict__ list,
                               int* __restrict__ counters,
                               const float* __restrict__ xsq_part, float* __restrict__ v1_part,
                               float* __restrict__ out_loss) {
    const int tid = threadIdx.x;
    const int p = blockIdx.x * 256 + tid;
    float4 ma = *(const float4*)&ws_m1[(size_t)p * NSPLIT];
    float4 mb = *(const float4*)&ws_m1[(size_t)p * NSPLIT + 4];
    float m[8] = { ma.x, ma.y, ma.z, ma.w, mb.x, mb.y, mb.z, mb.w };
    float v1 = m[0]; int sstar = 0;
#pragma unroll
    for (int s = 1; s < NSPLIT; ++s)
        if (m[s] < v1) { v1 = m[s]; sstar = s; }
    float thr = v1 + MARGIN;                // same rounded op as dist's ballot threshold
    bool flag = false;
#pragma unroll
    for (int s = 0; s < NSPLIT; ++s)
        if (s != sstar && m[s] <= thr) flag = true;
    uint4 w4 = *(const uint4*)&cand[((size_t)p * NSPLIT + sstar) * 4];
    int pc = __builtin_popcount(w4.x) + __builtin_popcount(w4.y)
           + __builtin_popcount(w4.z) + __builtin_popcount(w4.w);
    flag = flag || (pc > 1);
    int idx;
    if (w4.x)      idx = __builtin_ctz(w4.x);
    else if (w4.y) idx = 32 + __builtin_ctz(w4.y);
    else if (w4.z) idx = 64 + __builtin_ctz(w4.z);
    else           idx = 96 + __builtin_ctz(w4.w);
    final_idx[p] = sstar * BKC + idx;
    if (flag) {
        int slot = atomicAdd(&counters[0], 1);
        list[slot] = p;
    }

    // block partial of sum v1 (loss = 1.25*(sum v1 + sum x^2)/(N*D), error ~3e-7)
    __shared__ float red[256];
    red[tid] = v1;
    __syncthreads();
#pragma unroll
    for (int s = 128; s > 0; s >>= 1) {
        if (tid < s) red[tid] += red[tid + s];
        __syncthreads();
    }
    if (tid == 0) v1_part[blockIdx.x] = red[0];

    __shared__ int amlast;
    if (tid == 0) {
        __threadfence();
        amlast = (atomicAdd(&counters[32], 1) == (int)gridDim.x - 1);
    }
    __syncthreads();
    if (amlast) {
        __threadfence();
        double s = 0.0;
        for (int i = tid; i < CVT_BLOCKS; i += 256) s += (double)xsq_part[i];
        for (int i = tid; i < NPTS / 256; i += 256) s += (double)v1_part[i];
        __shared__ double dred[256];
        dred[tid] = s;
        __syncthreads();
#pragma unroll
        for (int t = 128; t > 0; t >>= 1) {
            if (tid < t) dred[tid] += dred[tid + t];
            __syncthreads();
        }
        if (tid == 0)
            out_loss[0] = (float)(1.25 * dred[0] / (double)((size_t)NPTS * DIM));
    }
}

// ------- phase 3: np-emulating rescore over candidate bitmaps (R12 verbatim) -------
// One flagged point per wave; lane<32 owns one bitmap word; per set bit:
// d = fl32(fl32(A - 2*B) + C), B = sequential ascending-d fp32 fma chain,
// A = np-pairwise sum x^2, C = Cnp — bit-identical to rounds 3-12.
__global__ __launch_bounds__(256) void rescore_np_kernel(
        const float* __restrict__ X, const float* __restrict__ E,
        const float* __restrict__ Cnp, const unsigned int* __restrict__ cand,
        const int* __restrict__ list, const int* __restrict__ counters,
        int* __restrict__ final_idx) {
#pragma clang fp contract(off)
    const int tid = threadIdx.x;
    const int lane = tid & 63;
    const int wave = tid >> 6;
    const int cnt = counters[0];
    __shared__ float xsh[4][DIM];

    for (int base = blockIdx.x * 4; base < cnt; base += gridDim.x * 4) {
        const int li = base + wave;
        const bool active = (li < cnt);
        const int p = list[active ? li : (cnt - 1)];
        __syncthreads();
        *(float4*)&xsh[wave][lane * 4] = *(const float4*)(X + (size_t)p * DIM + lane * 4);
        __syncthreads();

        float s = 0.f;
        if (lane < 16) {
            const int h = lane >> 3, j = lane & 7;
            float v = xsh[wave][h * 128 + j];
            s = v * v;
            for (int i = 8; i < 128; i += 8) {
                float w = xsh[wave][h * 128 + i + j];
                s += w * w;
            }
        }
        float t0 = __shfl(s, 0), t1 = __shfl(s, 1), t2 = __shfl(s, 2), t3 = __shfl(s, 3);
        float t4 = __shfl(s, 4), t5 = __shfl(s, 5), t6 = __shfl(s, 6), t7 = __shfl(s, 7);
        float u0 = __shfl(s, 8), u1 = __shfl(s, 9), u2 = __shfl(s, 10), u3 = __shfl(s, 11);
        float u4 = __shfl(s, 12), u5 = __shfl(s, 13), u6 = __shfl(s, 14), u7 = __shfl(s, 15);
        const float A = (((t0 + t1) + (t2 + t3)) + ((t4 + t5) + (t6 + t7)))
                      + (((u0 + u1) + (u2 + u3)) + ((u4 + u5) + (u6 + u7)));

        float bv = 3.4e38f; int bi = 0x7FFFFFFF;
        if (lane < 32) {
            unsigned int bits = cand[(size_t)p * 32 + lane];
            const int cb = (lane >> 2) * 128 + (lane & 3) * 32;
            while (bits) {
                int t = __builtin_ctz(bits);
                bits &= bits - 1;
                int c = cb + t;
                const float4* er4 = (const float4*)(E + (size_t)c * DIM);
                float acc = 0.f;
                for (int d4 = 0; d4 < DIM / 4; ++d4) {
                    float4 e4 = er4[d4];
                    float4 x4 = *(const float4*)&xsh[wave][d4 * 4];
                    acc = __builtin_fmaf(x4.x, e4.x, acc);
                    acc = __builtin_fmaf(x4.y, e4.y, acc);
                    acc = __builtin_fmaf(x4.z, e4.z, acc);
                    acc = __builtin_fmaf(x4.w, e4.w, acc);
                }
                float tt = A - 2.0f * acc;
                float dnp = tt + Cnp[c];
                if (dnp < bv) { bv = dnp; bi = c; }
            }
        }
#pragma unroll
        for (int m = 1; m < 64; m <<= 1) {
            float ov = __shfl_xor(bv, m);
            int oi = __shfl_xor(bi, m);
            if (ov < bv || (ov == bv && oi < bi)) { bv = ov; bi = oi; }
        }
        if (active && lane == 0) final_idx[p] = bi;
    }
}

// ------- phase 4: gather — write quantized rows + indices (no X read) -------
__global__ void gather_kernel(const float* __restrict__ E, const int* __restrict__ final_idx,
                              float* __restrict__ out_q, float* __restrict__ out_idx) {
    const int tid = threadIdx.x;
    const int p = blockIdx.x * 16 + (tid >> 4);
    const int c = tid & 15;
    const int bi = final_idx[p];
#pragma unroll
    for (int k = 0; k < 4; ++k) {
        int d4 = c + k * 16;
        float4 e4 = *(const float4*)(E + (size_t)bi * DIM + d4 * 4);
        *(float4*)(out_q + (size_t)p * DIM + d4 * 4) = e4;
    }
    if (c == 0) out_idx[p] = (float)bi;
}

extern "C" void kernel_launch(void* const* d_in, const int* in_sizes, int n_in,
                              void* d_out, int out_size, void* d_ws, size_t ws_size,
                              hipStream_t stream) {
    const float* X = (const float*)d_in[0];   // [32768, 256]
    const float* E = (const float*)d_in[1];   // [1024, 256]
    float* out = (float*)d_out;
    float* out_q = out;                                 // 8388608 floats
    float* out_loss = out + (size_t)NPTS * DIM;         // 1 float
    float* out_idx = out + (size_t)NPTS * DIM + 1;      // 32768 floats

    // staging inside out_q (fully rewritten by gather afterward):
    // Xb (16.8MB) + Eb (0.5MB) + cand (4.2MB) = 21.5MB < 33.5MB
    unsigned short* Xb = (unsigned short*)d_out;
    unsigned short* Eb = Xb + (size_t)NPTS * DIM;
    unsigned int* cand = (unsigned int*)(Eb + (size_t)KCODES * DIM);  // [NPTS][8][4] u32

    float* ws = (float*)d_ws;
    float* Cnp = ws;                                    // 1024
    float* ws_m1 = Cnp + KCODES;                        // [NPTS][8] floats (1MB)
    int* final_idx = (int*)(ws_m1 + (size_t)NPTS * NSPLIT);  // 32768 ints
    int* counters = final_idx + NPTS;                   // 64 ints ([0]=flag cnt, [32]=done)
    int* list = counters + 64;                          // 32768 ints
    float* xsq_part = (float*)(list + NPTS);            // 2048 floats
    float* v1_part = xsq_part + CVT_BLOCKS;             // 128 floats

    convert_kernel<<<CVT_BLOCKS + KCODES / 256, 256, 0, stream>>>(X, E, Xb, Eb, Cnp,
                                                                  xsq_part, counters);
    dist_kernel<<<dim3(NPTS / BN, NSPLIT), 256, 0, stream>>>(Xb, Eb, Cnp, ws_m1, cand);
    resolve_kernel<<<NPTS / 256, 256, 0, stream>>>(ws_m1, cand, final_idx, list, counters,
                                                   xsq_part, v1_part, out_loss);
    rescore_np_kernel<<<512, 256, 0, stream>>>(X, E, Cnp, cand, list, counters, final_idx);
    gather_kernel<<<NPTS / 16, 256, 0, stream>>>(E, final_idx, out_q, out_idx);
}